// Round 13
// baseline (47.006 us; speedup 1.0000x reference)
//
#include <hip/hip_runtime.h>
#include <math.h>

// densemap = sum_k c_k * log2(relu(k^2 * conv_k(x)) + 1)
// conv_k = separable Gaussian (sigma = k/2), TF-SAME padding: pad_lo = (k-1)/2.
// Column/row window offsets union: -2..+3 (6 wide). k=1 kernel == identity.
//
// Tile: 64x64 outputs per block (block 64x4, 16 rows/wave), staged 69x72 LDS
// (19.87 KB -> exactly 8 blocks/CU at the 256-thread cap). Halo amortization
// 21/16 = 1.31x vs 13/8 = 1.625x at RPT=8. Min-depth rings (25 floats),
// straight-line macro expansion (all indices ICEs), alternating p/q register
// prefetch of the next staged row.
//
// R12 bug fixed: the p/q alternation ends with row 20 in q (STEPA(14) loads
// it), so the final step STEPAL(15) must consume the q set, not p.

struct Weights {
    // horizontal symmetric-pair coefficients (prescaled by k^2)
    float h6a, h6b, h6c, h5a, h5b, h5c, h4a, h4b, h3a, h3b, h2c;
    // vertical symmetric-pair coefficients
    float v6a, v6b, v6c, v5a, v5b, v5c, v4a, v4b, v3a, v3b, v2a;
    float c[6];     // regression slope coefficients
};

#define TXO 64
#define TYO 64
#define RPT 16          // rows per thread (block 64x4)
#define LDSW 72         // floats per staged row (16B-aligned stride)
#define SROWS 69        // staged rows: outputs -2..+66
#define NF4 (SROWS * 18)  // 1242 float4s per tile

#define GLOAD_LDS16(gp, lp) __builtin_amdgcn_global_load_lds( \
    (const __attribute__((address_space(1))) unsigned int*)(gp), \
    (__attribute__((address_space(3))) unsigned int*)(lp), 16, 0, 0)

__global__ __launch_bounds__(256, 8) void ldeb_kernel(const float* __restrict__ x,
                                                      float* __restrict__ out,
                                                      Weights W) {
    __shared__ float xs[SROWS * LDSW];
    const int img = blockIdx.z;
    const int bx = blockIdx.x, by = blockIdx.y;
    const int x0a = bx * TXO - 4;      // aligned staged-col base
    const int y0 = by * TYO - 2;       // staged-row base
    const float* __restrict__ xb = x + (size_t)img * 262144;
    const int tid = threadIdx.y * 64 + threadIdx.x;

    if (bx >= 1 && bx <= 6 && by >= 1 && by <= 6) {
        // interior: direct global->LDS, 16B/lane, dest linear in tid
#pragma unroll
        for (int it = 0; it < 5; ++it) {
            int i = tid + it * 256;
            if (i < NF4) {
                int row = i / 18;
                int c4 = i - row * 18;
                const float* gp = xb + (size_t)(y0 + row) * 512 + x0a + 4 * c4;
                GLOAD_LDS16(gp, &xs[i * 4]);
            }
        }
    } else {
        // border: reg-staged float4 with whole-float4 zero-fill
#pragma unroll
        for (int it = 0; it < 5; ++it) {
            int i = tid + it * 256;
            if (i < NF4) {
                int row = i / 18;
                int c4 = i - row * 18;
                int gy = y0 + row;
                int gc = x0a + 4 * c4;
                float4 v = make_float4(0.f, 0.f, 0.f, 0.f);
                if ((unsigned)gy < 512u && (unsigned)gc < 512u)
                    v = *(const float4*)(xb + (size_t)gy * 512 + gc);
                *(float4*)&xs[i * 4] = v;
            }
        }
    }
    __syncthreads();

    const int lane = threadIdx.x;        // local col 0..63
    const int Lr0 = threadIdx.y * RPT;   // this wave's staged-row base
    const float* __restrict__ base = &xs[Lr0 * LDSW + lane + 2];
    float* __restrict__ ob = out + (size_t)img * 262144
                           + (size_t)(by * TYO + Lr0) * 512 + bx * TXO + lane;

    float h6[6], h5[5], h4[4], h3[4], h2[3], h1[3];  // all indices ICEs
    float p0, p1, p2, p3, p4, p5;   // prefetched row (even steps consume)
    float q0, q1, q2, q3, q4, q5;   // prefetched row (odd steps consume)

#define LOG1(s) __builtin_amdgcn_logf(fmaxf((s), 0.0f) + 1.0f)

// prologue row j = 0..4: fill rings only (direct reads)
#define PROW(j) { \
        const float* row = base + (j) * LDSW; \
        float v0 = row[0], v1 = row[1], v2 = row[2], \
              v3 = row[3], v4 = row[4], v5 = row[5]; \
        float s05 = v0 + v5, s14 = v1 + v4, s23 = v2 + v3; \
        float s04 = v0 + v4, s13 = v1 + v3; \
        h6[(j) % 6] = W.h6a * s05 + W.h6b * s14 + W.h6c * s23; \
        h5[(j) % 5] = W.h5a * s04 + W.h5b * s13 + W.h5c * v2; \
        h4[(j) % 4] = W.h4a * s14 + W.h4b * s23; \
        h3[(j) % 4] = W.h3a * s13 + W.h3b * v2; \
        h2[(j) % 3] = W.h2c * s23; \
        h1[(j) % 3] = v2; \
    }

#define LOADREGS(j, a0, a1, a2, a3, a4, a5) { \
        const float* row = base + (j) * LDSW; \
        a0 = row[0]; a1 = row[1]; a2 = row[2]; \
        a3 = row[3]; a4 = row[4]; a5 = row[5]; \
    }

// core of a step: consume row regs (staged row r+5), emit output row r
#define STEPCORE(r, v0, v1, v2, v3, v4, v5) { \
        float s05 = v0 + v5, s14 = v1 + v4, s23 = v2 + v3; \
        float s04 = v0 + v4, s13 = v1 + v3; \
        float H6 = W.h6a * s05 + W.h6b * s14 + W.h6c * s23; \
        float t6 = W.v6a * (h6[(r) % 6] + H6) \
                 + W.v6b * (h6[((r) + 1) % 6] + h6[((r) + 4) % 6]) \
                 + W.v6c * (h6[((r) + 2) % 6] + h6[((r) + 3) % 6]); \
        float t5 = W.v5a * (h5[(r) % 5] + h5[((r) + 4) % 5]) \
                 + W.v5b * (h5[((r) + 1) % 5] + h5[((r) + 3) % 5]) \
                 + W.v5c * h5[((r) + 2) % 5]; \
        float t4 = W.v4a * (h4[((r) + 1) % 4] + h4[((r) + 4) % 4]) \
                 + W.v4b * (h4[((r) + 2) % 4] + h4[((r) + 3) % 4]); \
        float t3 = W.v3a * (h3[((r) + 1) % 4] + h3[((r) + 3) % 4]) \
                 + W.v3b * h3[((r) + 2) % 4]; \
        float t2 = W.v2a * (h2[((r) + 2) % 3] + h2[((r) + 3) % 3]); \
        float t1 = h1[((r) + 5) % 3]; /* row r+2, read before overwrite */ \
        h6[((r) + 5) % 6] = H6; \
        h5[((r) + 5) % 5] = W.h5a * s04 + W.h5b * s13 + W.h5c * v2; \
        h4[((r) + 5) % 4] = W.h4a * s14 + W.h4b * s23; \
        h3[((r) + 5) % 4] = W.h3a * s13 + W.h3b * v2; \
        h2[((r) + 5) % 3] = W.h2c * s23; \
        h1[((r) + 5) % 3] = v2; \
        float res = fmaf(W.c[5], LOG1(t6), \
                    fmaf(W.c[4], LOG1(t5), \
                    fmaf(W.c[3], LOG1(t4), \
                    fmaf(W.c[2], LOG1(t3), \
                    fmaf(W.c[1], LOG1(t2), \
                         W.c[0] * LOG1(t1)))))); \
        ob[(r) * 512] = res; \
    }

// even step: consume p, prefetch into q; odd step: consume q, prefetch into p
#define STEPA(r) { LOADREGS((r) + 6, q0, q1, q2, q3, q4, q5) \
                   STEPCORE(r, p0, p1, p2, p3, p4, p5) }
#define STEPB(r) { LOADREGS((r) + 6, p0, p1, p2, p3, p4, p5) \
                   STEPCORE(r, q0, q1, q2, q3, q4, q5) }
// last step (r=15, odd parity): row 20 was prefetched into q by STEPA(14)
#define STEPAL(r) { STEPCORE(r, q0, q1, q2, q3, q4, q5) }

    PROW(0) PROW(1) PROW(2) PROW(3) PROW(4)
    LOADREGS(5, p0, p1, p2, p3, p4, p5)
    STEPA(0)  STEPB(1)  STEPA(2)  STEPB(3)
    STEPA(4)  STEPB(5)  STEPA(6)  STEPB(7)
    STEPA(8)  STEPB(9)  STEPA(10) STEPB(11)
    STEPA(12) STEPB(13) STEPA(14) STEPAL(15)

#undef STEPA
#undef STEPB
#undef STEPAL
#undef STEPCORE
#undef LOADREGS
#undef PROW
#undef LOG1
}

extern "C" void kernel_launch(void* const* d_in, const int* in_sizes, int n_in,
                              void* d_out, int out_size, void* d_ws, size_t ws_size,
                              hipStream_t stream) {
    const float* x = (const float*)d_in[0];
    float* out = (float*)d_out;

    Weights W;
    // regression coefficients: c_k = (X_k - mean(X)) / sum((X - mean)^2), X_k = log2(k)
    double X[6], mean = 0.0;
    for (int k = 1; k <= 6; ++k) { X[k - 1] = log2((double)k); mean += X[k - 1]; }
    mean /= 6.0;
    double denom = 0.0;
    for (int i = 0; i < 6; ++i) { double xc = X[i] - mean; denom += xc * xc; }
    for (int i = 0; i < 6; ++i) W.c[i] = (float)((X[i] - mean) / denom);

    // separable gaussian 1D weights, sigma = k/2
    float wh[6][6], wv[6][6];
    for (int k = 1; k <= 6; ++k) {
        double sigma = k / 2.0;
        double g[6], s = 0.0;
        for (int i = 0; i < k; ++i) {
            double a = i - (k - 1) / 2.0;
            g[i] = exp(-(a * a) / (2.0 * sigma * sigma));
            s += g[i];
        }
        for (int i = 0; i < 6; ++i) {
            if (i < k) {
                double gn = g[i] / s;
                wv[k - 1][i] = (float)gn;
                wh[k - 1][i] = (float)(gn * (double)(k * k)); // horizontal prescaled by k^2
            } else {
                wv[k - 1][i] = 0.0f;
                wh[k - 1][i] = 0.0f;
            }
        }
    }
    // symmetric-pair coefficients
    W.h6a = wh[5][0]; W.h6b = wh[5][1]; W.h6c = wh[5][2];
    W.h5a = wh[4][0]; W.h5b = wh[4][1]; W.h5c = wh[4][2];
    W.h4a = wh[3][0]; W.h4b = wh[3][1];
    W.h3a = wh[2][0]; W.h3b = wh[2][1];
    W.h2c = wh[1][0];
    W.v6a = wv[5][0]; W.v6b = wv[5][1]; W.v6c = wv[5][2];
    W.v5a = wv[4][0]; W.v5b = wv[4][1]; W.v5c = wv[4][2];
    W.v4a = wv[3][0]; W.v4b = wv[3][1];
    W.v3a = wv[2][0]; W.v3b = wv[2][1];
    W.v2a = wv[1][0];

    dim3 grid(512 / TXO, 512 / TYO, 64);
    dim3 block(64, 4, 1);
    hipLaunchKernelGGL(ldeb_kernel, grid, block, 0, stream, x, out, W);
}

// Round 14
// 42.098 us; speedup vs baseline: 1.1166x; 1.1166x over previous
//
#include <hip/hip_runtime.h>
#include <math.h>

// densemap = sum_k c_k * log2(relu(k^2 * conv_k(x)) + 1)
// conv_k = separable Gaussian (sigma = k/2), TF-SAME padding: pad_lo = (k-1)/2.
// Column/row window offsets union: -2..+3 (6 wide). k=1 kernel == identity.
//
// PACKED-FP32 2-COLUMN VARIANT (R10 schedule, widened):
// Tile 128x32 outputs per block (block 64x4, RPT=8); each lane computes 2
// adjacent columns via CDNA VOP3P packed fp32 (v_pk_add/mul/fma_f32) -- every
// conv ALU op processes both columns at full rate, halving conv VALU.
// k^2 prescale removed from H weights and folded into the log argument as
// log2(fma(k^2, max(t,0), 1)) (the +1 add becomes the fma) -> horizontal
// weights == vertical weights, only 11 broadcast f32x2 weight pairs.
// Taps u0..u6 load as 6 f32x2 pairs: even pairs {u0,u1},{u2,u3},{u4,u5} are
// 8B-aligned ds_read_b64; odd pairs {u1,u2},{u3,u4},{u5,u6} are ds_read2_b32.
// S05={u0+u5,u1+u6}=E0+O2, S14=O0+E2, S23=E1+O1, S04=E0+E2, S13=O0+O1, V2=E1.
// Ring schedule identical to R10 (verified passing).

typedef float f32x2 __attribute__((ext_vector_type(2)));

struct Weights {
    float w6a, w6b, w6c, w5a, w5b, w5c, w4a, w4b, w3a, w3b, w2a; // 1D gaussian
    float c[6];     // regression slope coefficients
};

#define TXO 128
#define TYO 32
#define RPT 8           // rows per thread (block 64x4)
#define LDSW 136        // floats per staged row (16B-aligned stride)
#define SROWS 37        // staged rows: outputs -2..+34
#define NF4 (SROWS * 34)  // 1258 float4s per tile

#define GLOAD_LDS16(gp, lp) __builtin_amdgcn_global_load_lds( \
    (const __attribute__((address_space(1))) unsigned int*)(gp), \
    (__attribute__((address_space(3))) unsigned int*)(lp), 16, 0, 0)

#define PKADD(a, b) ({ f32x2 _d; \
    asm("v_pk_add_f32 %0, %1, %2" : "=v"(_d) : "v"(a), "v"(b)); _d; })
#define PKMUL(a, b) ({ f32x2 _d; \
    asm("v_pk_mul_f32 %0, %1, %2" : "=v"(_d) : "v"(a), "v"(b)); _d; })
#define PKFMA(a, b, c) ({ f32x2 _d; \
    asm("v_pk_fma_f32 %0, %1, %2, %3" : "=v"(_d) : "v"(a), "v"(b), "v"(c)); _d; })

__global__ __launch_bounds__(256, 4) void ldeb_kernel(const float* __restrict__ x,
                                                      float* __restrict__ out,
                                                      Weights W) {
    __shared__ float xs[SROWS * LDSW];
    const int img = blockIdx.z;
    const int bx = blockIdx.x, by = blockIdx.y;
    const int x0a = bx * TXO - 4;      // aligned staged-col base
    const int y0 = by * TYO - 2;       // staged-row base
    const float* __restrict__ xb = x + (size_t)img * 262144;
    const int tid = threadIdx.y * 64 + threadIdx.x;

    if (bx >= 1 && bx <= 2 && by >= 1 && by <= 14) {
        // interior: direct global->LDS, 16B/lane, dest linear in tid
#pragma unroll
        for (int it = 0; it < 5; ++it) {
            int i = tid + it * 256;
            if (i < NF4) {
                int row = i / 34;
                int c4 = i - row * 34;
                const float* gp = xb + (size_t)(y0 + row) * 512 + x0a + 4 * c4;
                GLOAD_LDS16(gp, &xs[i * 4]);
            }
        }
    } else {
        // border: reg-staged float4 with whole-float4 zero-fill
#pragma unroll
        for (int it = 0; it < 5; ++it) {
            int i = tid + it * 256;
            if (i < NF4) {
                int row = i / 34;
                int c4 = i - row * 34;
                int gy = y0 + row;
                int gc = x0a + 4 * c4;
                float4 v = make_float4(0.f, 0.f, 0.f, 0.f);
                if ((unsigned)gy < 512u && (unsigned)gc < 512u)
                    v = *(const float4*)(xb + (size_t)gy * 512 + gc);
                *(float4*)&xs[i * 4] = v;
            }
        }
    }
    __syncthreads();

    const int lane = threadIdx.x;        // 0..63; owns cols 2*lane, 2*lane+1
    const int Lr0 = threadIdx.y * RPT;   // this wave's staged-row base
    // tap -2 of col (bx*128 + 2*lane) is staged col 2*lane + 2
    const float* __restrict__ base = &xs[Lr0 * LDSW + 2 * lane + 2];
    float* __restrict__ ob = out + (size_t)img * 262144
                           + (size_t)(by * TYO + Lr0) * 512 + bx * TXO + 2 * lane;

    // broadcast weight pairs (one-time v_movs, hoisted)
    const f32x2 w6a = {W.w6a, W.w6a}, w6b = {W.w6b, W.w6b}, w6c = {W.w6c, W.w6c};
    const f32x2 w5a = {W.w5a, W.w5a}, w5b = {W.w5b, W.w5b}, w5c = {W.w5c, W.w5c};
    const f32x2 w4a = {W.w4a, W.w4a}, w4b = {W.w4b, W.w4b};
    const f32x2 w3a = {W.w3a, W.w3a}, w3b = {W.w3b, W.w3b};
    const f32x2 w2a = {W.w2a, W.w2a};

    f32x2 h6[6], h5[5], h4[4], h3[4], h2[3], h1[3];  // all indices ICEs

#define LOADP(dst, fptr) __builtin_memcpy(&(dst), (fptr), 8)

// load row j's 6 tap-pairs and form packed column-pair sums
#define ROWSUMS(j) \
        f32x2 E0, O0, E1, O1, E2, O2; \
        { const float* rp = base + (j) * LDSW; \
          LOADP(E0, rp);     LOADP(O0, rp + 1); \
          LOADP(E1, rp + 2); LOADP(O1, rp + 3); \
          LOADP(E2, rp + 4); LOADP(O2, rp + 5); } \
        f32x2 S05 = PKADD(E0, O2), S14 = PKADD(O0, E2), S23 = PKADD(E1, O1); \
        f32x2 S04 = PKADD(E0, E2), S13 = PKADD(O0, O1), V2 = E1;

// prologue row j = 0..4: fill rings only
#define PROW(j) { \
        ROWSUMS(j) \
        h6[(j) % 6] = PKFMA(w6c, S23, PKFMA(w6b, S14, PKMUL(w6a, S05))); \
        h5[(j) % 5] = PKFMA(w5c, V2,  PKFMA(w5b, S13, PKMUL(w5a, S04))); \
        h4[(j) % 4] = PKFMA(w4b, S23, PKMUL(w4a, S14)); \
        h3[(j) % 4] = PKFMA(w3b, V2,  PKMUL(w3a, S13)); \
        h2[(j) % 3] = PKMUL(w2a, S23); \
        h1[(j) % 3] = V2; \
    }

// y = log2(k2 * max(t,0) + 1), native v_log_f32
#define SLOG(t, k2) __builtin_amdgcn_logf(fmaf((k2), fmaxf((t), 0.0f), 1.0f))

// step r: read staged row r+5, emit output row r (both columns)
#define STEPR(r) { \
        ROWSUMS((r) + 5) \
        f32x2 H6 = PKFMA(w6c, S23, PKFMA(w6b, S14, PKMUL(w6a, S05))); \
        f32x2 t6 = PKMUL(w6a, PKADD(h6[(r) % 6], H6)); \
        t6 = PKFMA(w6b, PKADD(h6[((r) + 1) % 6], h6[((r) + 4) % 6]), t6); \
        t6 = PKFMA(w6c, PKADD(h6[((r) + 2) % 6], h6[((r) + 3) % 6]), t6); \
        f32x2 t5 = PKMUL(w5a, PKADD(h5[(r) % 5], h5[((r) + 4) % 5])); \
        t5 = PKFMA(w5b, PKADD(h5[((r) + 1) % 5], h5[((r) + 3) % 5]), t5); \
        t5 = PKFMA(w5c, h5[((r) + 2) % 5], t5); \
        f32x2 t4 = PKMUL(w4a, PKADD(h4[((r) + 1) % 4], h4[((r) + 4) % 4])); \
        t4 = PKFMA(w4b, PKADD(h4[((r) + 2) % 4], h4[((r) + 3) % 4]), t4); \
        f32x2 t3 = PKMUL(w3a, PKADD(h3[((r) + 1) % 4], h3[((r) + 3) % 4])); \
        t3 = PKFMA(w3b, h3[((r) + 2) % 4], t3); \
        f32x2 t2 = PKMUL(w2a, PKADD(h2[((r) + 2) % 3], h2[((r) + 3) % 3])); \
        f32x2 t1 = h1[((r) + 5) % 3]; /* row r+2, read before overwrite */ \
        h6[((r) + 5) % 6] = H6; \
        h5[((r) + 5) % 5] = PKFMA(w5c, V2,  PKFMA(w5b, S13, PKMUL(w5a, S04))); \
        h4[((r) + 5) % 4] = PKFMA(w4b, S23, PKMUL(w4a, S14)); \
        h3[((r) + 5) % 4] = PKFMA(w3b, V2,  PKMUL(w3a, S13)); \
        h2[((r) + 5) % 3] = PKMUL(w2a, S23); \
        h1[((r) + 5) % 3] = V2; \
        f32x2 res; \
        res.x = fmaf(W.c[5], SLOG(t6.x, 36.0f), \
                fmaf(W.c[4], SLOG(t5.x, 25.0f), \
                fmaf(W.c[3], SLOG(t4.x, 16.0f), \
                fmaf(W.c[2], SLOG(t3.x, 9.0f), \
                fmaf(W.c[1], SLOG(t2.x, 4.0f), \
                     W.c[0] * SLOG(t1.x, 1.0f)))))); \
        res.y = fmaf(W.c[5], SLOG(t6.y, 36.0f), \
                fmaf(W.c[4], SLOG(t5.y, 25.0f), \
                fmaf(W.c[3], SLOG(t4.y, 16.0f), \
                fmaf(W.c[2], SLOG(t3.y, 9.0f), \
                fmaf(W.c[1], SLOG(t2.y, 4.0f), \
                     W.c[0] * SLOG(t1.y, 1.0f)))))); \
        __builtin_memcpy(ob + (size_t)(r) * 512, &res, 8); \
    }

    PROW(0) PROW(1) PROW(2) PROW(3) PROW(4)
    STEPR(0) STEPR(1) STEPR(2) STEPR(3)
    STEPR(4) STEPR(5) STEPR(6) STEPR(7)

#undef STEPR
#undef PROW
#undef ROWSUMS
#undef LOADP
#undef SLOG
}

extern "C" void kernel_launch(void* const* d_in, const int* in_sizes, int n_in,
                              void* d_out, int out_size, void* d_ws, size_t ws_size,
                              hipStream_t stream) {
    const float* x = (const float*)d_in[0];
    float* out = (float*)d_out;

    Weights W;
    // regression coefficients: c_k = (X_k - mean(X)) / sum((X - mean)^2), X_k = log2(k)
    double X[6], mean = 0.0;
    for (int k = 1; k <= 6; ++k) { X[k - 1] = log2((double)k); mean += X[k - 1]; }
    mean /= 6.0;
    double denom = 0.0;
    for (int i = 0; i < 6; ++i) { double xc = X[i] - mean; denom += xc * xc; }
    for (int i = 0; i < 6; ++i) W.c[i] = (float)((X[i] - mean) / denom);

    // separable gaussian 1D weights, sigma = k/2 (NOT k^2-prescaled; k^2 is
    // folded into the kernel's log argument)
    float wv[6][6];
    for (int k = 1; k <= 6; ++k) {
        double sigma = k / 2.0;
        double g[6], s = 0.0;
        for (int i = 0; i < k; ++i) {
            double a = i - (k - 1) / 2.0;
            g[i] = exp(-(a * a) / (2.0 * sigma * sigma));
            s += g[i];
        }
        for (int i = 0; i < 6; ++i)
            wv[k - 1][i] = (i < k) ? (float)(g[i] / s) : 0.0f;
    }
    W.w6a = wv[5][0]; W.w6b = wv[5][1]; W.w6c = wv[5][2];
    W.w5a = wv[4][0]; W.w5b = wv[4][1]; W.w5c = wv[4][2];
    W.w4a = wv[3][0]; W.w4b = wv[3][1];
    W.w3a = wv[2][0]; W.w3b = wv[2][1];
    W.w2a = wv[1][0];

    dim3 grid(512 / TXO, 512 / TYO, 64);
    dim3 block(64, 4, 1);
    hipLaunchKernelGGL(ldeb_kernel, grid, block, 0, stream, x, out, W);
}